// Round 1
// baseline (895.467 us; speedup 1.0000x reference)
//
#include <hip/hip_runtime.h>
#include <hip/hip_bf16.h>

typedef unsigned short u16;
typedef unsigned int u32;
typedef float f32x4 __attribute__((ext_vector_type(4)));
typedef __bf16 bf16x8 __attribute__((ext_vector_type(8)));

#define AS1 __attribute__((address_space(1)))
#define AS3 __attribute__((address_space(3)))

// ---- constants -------------------------------------------------------------
// M = B*T = 32768 tokens, D = 768, H = 2048
#define MTOT 32768
#define DK   768
#define HN   2048

// Octonion tables: Big[i*A+a][c*B+b] = S2[i][c] * w[J[i][c]][a][b]
// (each Cayley row is an involution, so J == K row)
__constant__ signed char J_TAB[64] = {
  0,1,2,3,4,5,6,7,
  1,0,3,2,5,4,7,6,
  2,3,0,1,6,7,4,5,
  3,2,1,0,7,6,5,4,
  4,5,6,7,0,1,2,3,
  5,4,7,6,1,0,3,2,
  6,7,4,5,2,3,0,1,
  7,6,5,4,3,2,1,0};
__constant__ signed char S_TAB[64] = {
   1, 1, 1, 1, 1, 1, 1, 1,
  -1, 1,-1, 1,-1, 1, 1,-1,
  -1, 1, 1,-1,-1,-1, 1, 1,
  -1,-1, 1, 1,-1, 1,-1, 1,
  -1, 1, 1, 1, 1,-1,-1,-1,
  -1,-1, 1,-1, 1, 1, 1,-1,
  -1,-1,-1, 1, 1,-1, 1, 1,
  -1, 1,-1,-1, 1, 1,-1, 1};

// ---- helpers ---------------------------------------------------------------
__device__ __forceinline__ u16 f2bf(float f) {  // RNE float->bf16
  u32 x = __float_as_uint(f);
  x += 0x7fffu + ((x >> 16) & 1u);
  return (u16)(x >> 16);
}

__device__ __forceinline__ void gload_lds16(const void* g, void* l) {
  // async global->LDS, 16B per lane; LDS dest = wave-uniform base + lane*16
  __builtin_amdgcn_global_load_lds((AS1 void*)(g), (AS3 void*)(l), 16, 0, 0);
}

// Stage ROWS x 64 bf16 tile (row-major, leading dim ldk) into contiguous LDS.
// Chunk = 8 bf16 (16B). XOR swizzle: global chunk c lives at LDS slot c^(row&7)
// so that fragment reads (row stride = 128B) spread across all banks.
template <int ROWS>
__device__ __forceinline__ void stage_tile(const u16* __restrict__ src, int ldk,
                                           u16* lds, int tid) {
#pragma unroll
  for (int f0 = 0; f0 < ROWS * 8; f0 += 256) {
    int flat = f0 + tid;
    int row = flat >> 3;
    int c = (flat & 7) ^ (row & 7);
    gload_lds16(src + row * ldk + c * 8, lds + (f0 + (tid & 192)) * 8);
  }
}

// Read one MFMA fragment (16B) from a swizzled 64-col tile.
// cbase = ks*4 + quad  (chunk index along K), row = tile row.
__device__ __forceinline__ bf16x8 frag64(const u16* lds, int row, int cbase) {
  int c = cbase ^ (row & 7);
  return *(const bf16x8*)(lds + row * 64 + c * 8);
}

// ---- prep kernels ----------------------------------------------------------
__global__ void scales_kernel(const float* __restrict__ w0,
                              const float* __restrict__ w1,
                              const float* __restrict__ w2,
                              float* __restrict__ scales) {
  __shared__ float red[256];
  const float* w = (blockIdx.x == 0) ? w0 : (blockIdx.x == 1) ? w1 : w2;
  float s = 0.f;
  for (int i = threadIdx.x; i < 196608; i += 256) s += fabsf(w[i]);
  red[threadIdx.x] = s;
  __syncthreads();
  for (int off = 128; off; off >>= 1) {
    if (threadIdx.x < off) red[threadIdx.x] += red[threadIdx.x + off];
    __syncthreads();
  }
  if (threadIdx.x == 0) scales[blockIdx.x] = red[0] / 196608.f + 1e-8f;
}

// Build Big^T as [8B][8A] row-major bf16 with entries in {-1,0,+1}
// (absmean scale folded into GEMM epilogues).
__global__ void build_big_kernel(const float* __restrict__ w,
                                 const float* __restrict__ scales, int sidx,
                                 int A, int B, u16* __restrict__ dst) {
  int idx = blockIdx.x * 256 + threadIdx.x;  // n*K8 + k, exact grid
  int K8 = 8 * A;
  int n = idx / K8;
  int k = idx - n * K8;
  int i = k / A, a = k - i * A;
  int c = n / B, b = n - c * B;
  float scale = scales[sidx];
  int j = J_TAB[i * 8 + c];
  float q = rintf(w[(j * A + a) * B + b] / scale);
  q = fminf(1.f, fmaxf(-1.f, q));
  dst[idx] = f2bf(q * (float)S_TAB[i * 8 + c]);
}

__global__ void cvt_x_kernel(const float* __restrict__ x, u16* __restrict__ xb) {
  int gid = blockIdx.x * 256 + threadIdx.x;  // 8 floats per thread
  const float4* x4 = (const float4*)x;
  float4 v0 = x4[gid * 2], v1 = x4[gid * 2 + 1];
  uint4 o;
  o.x = (u32)f2bf(v0.x) | ((u32)f2bf(v0.y) << 16);
  o.y = (u32)f2bf(v0.z) | ((u32)f2bf(v0.w) << 16);
  o.z = (u32)f2bf(v1.x) | ((u32)f2bf(v1.y) << 16);
  o.w = (u32)f2bf(v1.z) | ((u32)f2bf(v1.w) << 16);
  ((uint4*)xb)[gid] = o;
}

// ---- GEMM1: [M x 768] @ {BigG,BigU} -> SiLU(g)*u, h bf16 [M x 2048] --------
// Block tile: 128(M) x 64(N), both gate and up. 4 waves: 2x2 over (M=64, N=32).
__global__ __launch_bounds__(256) void gemm1_kernel(
    const u16* __restrict__ xb, const u16* __restrict__ wg,
    const u16* __restrict__ wu, const float* __restrict__ scales,
    u16* __restrict__ h) {
  __shared__ __align__(16) u16 lA[128 * 64];
  __shared__ __align__(16) u16 lG[64 * 64];
  __shared__ __align__(16) u16 lU[64 * 64];
  const int tid = threadIdx.x;
  const int bn = blockIdx.x & 31;   // 32 N-tiles of 64 (fast dim: A-tile L2 reuse)
  const int bm = blockIdx.x >> 5;   // 256 M-tiles of 128
  const int m0 = bm * 128, n0 = bn * 64;
  const int lane = tid & 63, wave = tid >> 6;
  const int wm = wave >> 1, wn = wave & 1;
  const int l15 = lane & 15, quad = lane >> 4;

  f32x4 accG[4][2] = {};
  f32x4 accU[4][2] = {};

  const u16* aSrc = xb + m0 * DK;
  const u16* gSrc = wg + n0 * DK;
  const u16* uSrc = wu + n0 * DK;

  for (int k0 = 0; k0 < DK; k0 += 64) {
    stage_tile<128>(aSrc + k0, DK, lA, tid);
    stage_tile<64>(gSrc + k0, DK, lG, tid);
    stage_tile<64>(uSrc + k0, DK, lU, tid);
    __syncthreads();
#pragma unroll
    for (int ks = 0; ks < 2; ++ks) {
      const int cb = ks * 4 + quad;
      bf16x8 af[4], gf[2], uf[2];
#pragma unroll
      for (int mi = 0; mi < 4; ++mi)
        af[mi] = frag64(lA, wm * 64 + mi * 16 + l15, cb);
#pragma unroll
      for (int ni = 0; ni < 2; ++ni) {
        gf[ni] = frag64(lG, wn * 32 + ni * 16 + l15, cb);
        uf[ni] = frag64(lU, wn * 32 + ni * 16 + l15, cb);
      }
#pragma unroll
      for (int mi = 0; mi < 4; ++mi)
#pragma unroll
        for (int ni = 0; ni < 2; ++ni) {
          accG[mi][ni] = __builtin_amdgcn_mfma_f32_16x16x32_bf16(
              af[mi], gf[ni], accG[mi][ni], 0, 0, 0);
          accU[mi][ni] = __builtin_amdgcn_mfma_f32_16x16x32_bf16(
              af[mi], uf[ni], accU[mi][ni], 0, 0, 0);
        }
    }
    __syncthreads();
  }

  const float sg = scales[0], su = scales[1];
#pragma unroll
  for (int mi = 0; mi < 4; ++mi)
#pragma unroll
    for (int ni = 0; ni < 2; ++ni)
#pragma unroll
      for (int r = 0; r < 4; ++r) {
        int m = m0 + wm * 64 + mi * 16 + quad * 4 + r;
        int n = n0 + wn * 32 + ni * 16 + l15;
        float g = accG[mi][ni][r] * sg;
        float u = accU[mi][ni][r] * su;
        float hv = g / (1.f + __expf(-g)) * u;  // silu(g)*u
        h[m * HN + n] = f2bf(hv);
      }
}

// ---- GEMM2: [M x 2048] @ BigD -> out fp32 [M x 768] ------------------------
// Block tile 128x128, 4 waves 2x2, each 64x64.
__global__ __launch_bounds__(256) void gemm2_kernel(
    const u16* __restrict__ h, const u16* __restrict__ wd,
    const float* __restrict__ scales, float* __restrict__ out) {
  __shared__ __align__(16) u16 lA[128 * 64];
  __shared__ __align__(16) u16 lB[128 * 64];
  const int tid = threadIdx.x;
  const int bn = blockIdx.x % 6;   // 6 N-tiles of 128
  const int bm = blockIdx.x / 6;   // 256 M-tiles
  const int m0 = bm * 128, n0 = bn * 128;
  const int lane = tid & 63, wave = tid >> 6;
  const int wm = wave >> 1, wn = wave & 1;
  const int l15 = lane & 15, quad = lane >> 4;

  f32x4 acc[4][4] = {};

  const u16* aSrc = h + m0 * HN;
  const u16* bSrc = wd + n0 * HN;

  for (int k0 = 0; k0 < HN; k0 += 64) {
    stage_tile<128>(aSrc + k0, HN, lA, tid);
    stage_tile<128>(bSrc + k0, HN, lB, tid);
    __syncthreads();
#pragma unroll
    for (int ks = 0; ks < 2; ++ks) {
      const int cb = ks * 4 + quad;
      bf16x8 af[4], bf[4];
#pragma unroll
      for (int mi = 0; mi < 4; ++mi)
        af[mi] = frag64(lA, wm * 64 + mi * 16 + l15, cb);
#pragma unroll
      for (int ni = 0; ni < 4; ++ni)
        bf[ni] = frag64(lB, wn * 64 + ni * 16 + l15, cb);
#pragma unroll
      for (int mi = 0; mi < 4; ++mi)
#pragma unroll
        for (int ni = 0; ni < 4; ++ni)
          acc[mi][ni] = __builtin_amdgcn_mfma_f32_16x16x32_bf16(
              af[mi], bf[ni], acc[mi][ni], 0, 0, 0);
    }
    __syncthreads();
  }

  const float sd = scales[2];
#pragma unroll
  for (int mi = 0; mi < 4; ++mi)
#pragma unroll
    for (int ni = 0; ni < 4; ++ni)
#pragma unroll
      for (int r = 0; r < 4; ++r) {
        int m = m0 + wm * 64 + mi * 16 + quad * 4 + r;
        int n = n0 + wn * 64 + ni * 16 + l15;
        out[m * DK + n] = acc[mi][ni][r] * sd;
      }
}

// ---- launch ----------------------------------------------------------------
extern "C" void kernel_launch(void* const* d_in, const int* in_sizes, int n_in,
                              void* d_out, int out_size, void* d_ws, size_t ws_size,
                              hipStream_t stream) {
  const float* x      = (const float*)d_in[0];
  const float* w_gate = (const float*)d_in[1];
  const float* w_up   = (const float*)d_in[2];
  const float* w_down = (const float*)d_in[3];
  float* out = (float*)d_out;

  // workspace layout (bytes), all 256-aligned:
  //  scales[4] | BigG^T 3MB | BigU^T 3MB | BigD^T 3MB | xb 50MB | h 134MB
  char* ws = (char*)d_ws;
  float* scales = (float*)ws;
  u16* wg = (u16*)(ws + 256);
  u16* wu = (u16*)(ws + 256 + 1u * 3145728u);
  u16* wd = (u16*)(ws + 256 + 2u * 3145728u);
  u16* xb = (u16*)(ws + 256 + 3u * 3145728u);
  u16* h  = (u16*)(ws + 256 + 3u * 3145728u + 50331648u);

  scales_kernel<<<3, 256, 0, stream>>>(w_gate, w_up, w_down, scales);
  build_big_kernel<<<6144, 256, 0, stream>>>(w_gate, scales, 0, 96, 256, wg);
  build_big_kernel<<<6144, 256, 0, stream>>>(w_up,   scales, 1, 96, 256, wu);
  build_big_kernel<<<6144, 256, 0, stream>>>(w_down, scales, 2, 256, 96, wd);
  cvt_x_kernel<<<12288, 256, 0, stream>>>(x, xb);
  gemm1_kernel<<<8192, 256, 0, stream>>>(xb, wg, wu, scales, h);
  gemm2_kernel<<<1536, 256, 0, stream>>>(h, wd, scales, out);
}

// Round 2
// 597.138 us; speedup vs baseline: 1.4996x; 1.4996x over previous
//
#include <hip/hip_runtime.h>
#include <hip/hip_bf16.h>

typedef unsigned short u16;
typedef unsigned int u32;
typedef float f32x4 __attribute__((ext_vector_type(4)));
typedef __bf16 bf16x8 __attribute__((ext_vector_type(8)));

#define AS1 __attribute__((address_space(1)))
#define AS3 __attribute__((address_space(3)))

// ---- constants -------------------------------------------------------------
// M = B*T = 32768 tokens, D = 768, H = 2048
#define MTOT 32768
#define DK   768
#define HN   2048

// Octonion tables: Big[i*A+a][c*B+b] = S2[i][c] * w[J[i][c]][a][b]
// (each Cayley row is an involution, so J == K row)
__constant__ signed char J_TAB[64] = {
  0,1,2,3,4,5,6,7,
  1,0,3,2,5,4,7,6,
  2,3,0,1,6,7,4,5,
  3,2,1,0,7,6,5,4,
  4,5,6,7,0,1,2,3,
  5,4,7,6,1,0,3,2,
  6,7,4,5,2,3,0,1,
  7,6,5,4,3,2,1,0};
__constant__ signed char S_TAB[64] = {
   1, 1, 1, 1, 1, 1, 1, 1,
  -1, 1,-1, 1,-1, 1, 1,-1,
  -1, 1, 1,-1,-1,-1, 1, 1,
  -1,-1, 1, 1,-1, 1,-1, 1,
  -1, 1, 1, 1, 1,-1,-1,-1,
  -1,-1, 1,-1, 1, 1, 1,-1,
  -1,-1,-1, 1, 1,-1, 1, 1,
  -1, 1,-1,-1, 1, 1,-1, 1};

// ---- helpers ---------------------------------------------------------------
__device__ __forceinline__ u16 f2bf(float f) {  // RNE float->bf16
  u32 x = __float_as_uint(f);
  x += 0x7fffu + ((x >> 16) & 1u);
  return (u16)(x >> 16);
}

__device__ __forceinline__ void gload_lds16(const void* g, void* l) {
  // async global->LDS, 16B per lane; LDS dest = wave-uniform base + lane*16
  __builtin_amdgcn_global_load_lds((AS1 void*)(g), (AS3 void*)(l), 16, 0, 0);
}

// Stage ROWS x 64 bf16 tile (row-major, leading dim ldk) into contiguous LDS.
// Chunk = 8 bf16 (16B). XOR swizzle: global chunk c lives at LDS slot c^(row&7)
// so that fragment reads (row stride = 128B) spread across all banks.
template <int ROWS>
__device__ __forceinline__ void stage_tile(const u16* __restrict__ src, int ldk,
                                           u16* lds, int tid) {
#pragma unroll
  for (int f0 = 0; f0 < ROWS * 8; f0 += 256) {
    int flat = f0 + tid;
    int row = flat >> 3;
    int c = (flat & 7) ^ (row & 7);
    gload_lds16(src + row * ldk + c * 8, lds + (f0 + (tid & 192)) * 8);
  }
}

// Read one MFMA fragment (16B) from a swizzled 64-col tile.
// cbase = ks*4 + quad  (chunk index along K), row = tile row.
__device__ __forceinline__ bf16x8 frag64(const u16* lds, int row, int cbase) {
  int c = cbase ^ (row & 7);
  return *(const bf16x8*)(lds + row * 64 + c * 8);
}

// ---- prep kernels ----------------------------------------------------------
// Two-stage deterministic absmean reduction (stage1: 576 blocks, 1 float4/thread)
__global__ void scales1_kernel(const float* __restrict__ w0,
                               const float* __restrict__ w1,
                               const float* __restrict__ w2,
                               float* __restrict__ partials) {
  __shared__ float red[256];
  const int t = blockIdx.x / 192;      // tensor id
  const int chunk = blockIdx.x % 192;  // 1024-float chunk
  const float* w = (t == 0) ? w0 : (t == 1) ? w1 : w2;
  const float4* w4 = (const float4*)(w + chunk * 1024);
  float4 v = w4[threadIdx.x];
  red[threadIdx.x] = fabsf(v.x) + fabsf(v.y) + fabsf(v.z) + fabsf(v.w);
  __syncthreads();
  for (int off = 128; off; off >>= 1) {
    if (threadIdx.x < off) red[threadIdx.x] += red[threadIdx.x + off];
    __syncthreads();
  }
  if (threadIdx.x == 0) partials[blockIdx.x] = red[0];
}

__global__ void scales2_kernel(const float* __restrict__ partials,
                               float* __restrict__ scales) {
  __shared__ float red[256];
  float s = (threadIdx.x < 192) ? partials[blockIdx.x * 192 + threadIdx.x] : 0.f;
  red[threadIdx.x] = s;
  __syncthreads();
  for (int off = 128; off; off >>= 1) {
    if (threadIdx.x < off) red[threadIdx.x] += red[threadIdx.x + off];
    __syncthreads();
  }
  if (threadIdx.x == 0) scales[blockIdx.x] = red[0] / 196608.f + 1e-8f;
}

// Build Big^T as [8B][8A] row-major bf16 with entries in {-1,0,+1}
// (absmean scale folded into GEMM epilogues).
__global__ void build_big_kernel(const float* __restrict__ w,
                                 const float* __restrict__ scales, int sidx,
                                 int A, int B, u16* __restrict__ dst) {
  int idx = blockIdx.x * 256 + threadIdx.x;  // n*K8 + k, exact grid
  int K8 = 8 * A;
  int n = idx / K8;
  int k = idx - n * K8;
  int i = k / A, a = k - i * A;
  int c = n / B, b = n - c * B;
  float scale = scales[sidx];
  int j = J_TAB[i * 8 + c];
  float q = rintf(w[(j * A + a) * B + b] / scale);
  q = fminf(1.f, fmaxf(-1.f, q));
  dst[idx] = f2bf(q * (float)S_TAB[i * 8 + c]);
}

__global__ void cvt_x_kernel(const float* __restrict__ x, u16* __restrict__ xb) {
  int gid = blockIdx.x * 256 + threadIdx.x;  // 8 floats per thread
  const float4* x4 = (const float4*)x;
  float4 v0 = x4[gid * 2], v1 = x4[gid * 2 + 1];
  uint4 o;
  o.x = (u32)f2bf(v0.x) | ((u32)f2bf(v0.y) << 16);
  o.y = (u32)f2bf(v0.z) | ((u32)f2bf(v0.w) << 16);
  o.z = (u32)f2bf(v1.x) | ((u32)f2bf(v1.y) << 16);
  o.w = (u32)f2bf(v1.z) | ((u32)f2bf(v1.w) << 16);
  ((uint4*)xb)[gid] = o;
}

// ---- GEMM1: [M x 768] @ {BigG,BigU} -> SiLU(g)*u, h bf16 [M x 2048] --------
// Block tile: 128(M) x 64(N), both gate and up. 4 waves: 2x2 over (M=64, N=32).
__global__ __launch_bounds__(256) void gemm1_kernel(
    const u16* __restrict__ xb, const u16* __restrict__ wg,
    const u16* __restrict__ wu, const float* __restrict__ scales,
    u16* __restrict__ h) {
  __shared__ __align__(16) u16 lA[128 * 64];
  __shared__ __align__(16) u16 lG[64 * 64];
  __shared__ __align__(16) u16 lU[64 * 64];
  const int tid = threadIdx.x;
  const int bn = blockIdx.x & 31;   // 32 N-tiles of 64 (fast dim: A-tile L2 reuse)
  const int bm = blockIdx.x >> 5;   // 256 M-tiles of 128
  const int m0 = bm * 128, n0 = bn * 64;
  const int lane = tid & 63, wave = tid >> 6;
  const int wm = wave >> 1, wn = wave & 1;
  const int l15 = lane & 15, quad = lane >> 4;

  f32x4 accG[4][2] = {};
  f32x4 accU[4][2] = {};

  const u16* aSrc = xb + m0 * DK;
  const u16* gSrc = wg + n0 * DK;
  const u16* uSrc = wu + n0 * DK;

  for (int k0 = 0; k0 < DK; k0 += 64) {
    stage_tile<128>(aSrc + k0, DK, lA, tid);
    stage_tile<64>(gSrc + k0, DK, lG, tid);
    stage_tile<64>(uSrc + k0, DK, lU, tid);
    __syncthreads();
#pragma unroll
    for (int ks = 0; ks < 2; ++ks) {
      const int cb = ks * 4 + quad;
      bf16x8 af[4], gf[2], uf[2];
#pragma unroll
      for (int mi = 0; mi < 4; ++mi)
        af[mi] = frag64(lA, wm * 64 + mi * 16 + l15, cb);
#pragma unroll
      for (int ni = 0; ni < 2; ++ni) {
        gf[ni] = frag64(lG, wn * 32 + ni * 16 + l15, cb);
        uf[ni] = frag64(lU, wn * 32 + ni * 16 + l15, cb);
      }
#pragma unroll
      for (int mi = 0; mi < 4; ++mi)
#pragma unroll
        for (int ni = 0; ni < 2; ++ni) {
          accG[mi][ni] = __builtin_amdgcn_mfma_f32_16x16x32_bf16(
              af[mi], gf[ni], accG[mi][ni], 0, 0, 0);
          accU[mi][ni] = __builtin_amdgcn_mfma_f32_16x16x32_bf16(
              af[mi], uf[ni], accU[mi][ni], 0, 0, 0);
        }
    }
    __syncthreads();
  }

  const float sg = scales[0], su = scales[1];
#pragma unroll
  for (int mi = 0; mi < 4; ++mi)
#pragma unroll
    for (int ni = 0; ni < 2; ++ni)
#pragma unroll
      for (int r = 0; r < 4; ++r) {
        int m = m0 + wm * 64 + mi * 16 + quad * 4 + r;
        int n = n0 + wn * 32 + ni * 16 + l15;
        float g = accG[mi][ni][r] * sg;
        float u = accU[mi][ni][r] * su;
        float hv = g / (1.f + __expf(-g)) * u;  // silu(g)*u
        h[m * HN + n] = f2bf(hv);
      }
}

// ---- GEMM2: [M x 2048] @ BigD -> out fp32 [M x 768] ------------------------
// Block tile 128x128, 4 waves 2x2, each 64x64.
__global__ __launch_bounds__(256) void gemm2_kernel(
    const u16* __restrict__ h, const u16* __restrict__ wd,
    const float* __restrict__ scales, float* __restrict__ out) {
  __shared__ __align__(16) u16 lA[128 * 64];
  __shared__ __align__(16) u16 lB[128 * 64];
  const int tid = threadIdx.x;
  const int bn = blockIdx.x % 6;   // 6 N-tiles of 128
  const int bm = blockIdx.x / 6;   // 256 M-tiles
  const int m0 = bm * 128, n0 = bn * 128;
  const int lane = tid & 63, wave = tid >> 6;
  const int wm = wave >> 1, wn = wave & 1;
  const int l15 = lane & 15, quad = lane >> 4;

  f32x4 acc[4][4] = {};

  const u16* aSrc = h + m0 * HN;
  const u16* bSrc = wd + n0 * HN;

  for (int k0 = 0; k0 < HN; k0 += 64) {
    stage_tile<128>(aSrc + k0, HN, lA, tid);
    stage_tile<128>(bSrc + k0, HN, lB, tid);
    __syncthreads();
#pragma unroll
    for (int ks = 0; ks < 2; ++ks) {
      const int cb = ks * 4 + quad;
      bf16x8 af[4], bf[4];
#pragma unroll
      for (int mi = 0; mi < 4; ++mi)
        af[mi] = frag64(lA, wm * 64 + mi * 16 + l15, cb);
#pragma unroll
      for (int ni = 0; ni < 4; ++ni)
        bf[ni] = frag64(lB, wn * 64 + ni * 16 + l15, cb);
#pragma unroll
      for (int mi = 0; mi < 4; ++mi)
#pragma unroll
        for (int ni = 0; ni < 4; ++ni)
          acc[mi][ni] = __builtin_amdgcn_mfma_f32_16x16x32_bf16(
              af[mi], bf[ni], acc[mi][ni], 0, 0, 0);
    }
    __syncthreads();
  }

  const float sd = scales[2];
#pragma unroll
  for (int mi = 0; mi < 4; ++mi)
#pragma unroll
    for (int ni = 0; ni < 4; ++ni)
#pragma unroll
      for (int r = 0; r < 4; ++r) {
        int m = m0 + wm * 64 + mi * 16 + quad * 4 + r;
        int n = n0 + wn * 64 + ni * 16 + l15;
        out[m * DK + n] = acc[mi][ni][r] * sd;
      }
}

// ---- launch ----------------------------------------------------------------
extern "C" void kernel_launch(void* const* d_in, const int* in_sizes, int n_in,
                              void* d_out, int out_size, void* d_ws, size_t ws_size,
                              hipStream_t stream) {
  const float* x      = (const float*)d_in[0];
  const float* w_gate = (const float*)d_in[1];
  const float* w_up   = (const float*)d_in[2];
  const float* w_down = (const float*)d_in[3];
  float* out = (float*)d_out;

  // workspace layout (bytes):
  //  scales[3] @0 | partials[576] @256 | BigG^T 3MB @4096 | BigU^T | BigD^T |
  //  xb 50MB | h 134MB
  char* ws = (char*)d_ws;
  float* scales   = (float*)ws;
  float* partials = (float*)(ws + 256);
  u16* wg = (u16*)(ws + 4096);
  u16* wu = (u16*)(ws + 4096 + 1u * 3145728u);
  u16* wd = (u16*)(ws + 4096 + 2u * 3145728u);
  u16* xb = (u16*)(ws + 4096 + 3u * 3145728u);
  u16* h  = (u16*)(ws + 4096 + 3u * 3145728u + 50331648u);

  scales1_kernel<<<576, 256, 0, stream>>>(w_gate, w_up, w_down, partials);
  scales2_kernel<<<3, 256, 0, stream>>>(partials, scales);
  build_big_kernel<<<6144, 256, 0, stream>>>(w_gate, scales, 0, 96, 256, wg);
  build_big_kernel<<<6144, 256, 0, stream>>>(w_up,   scales, 1, 96, 256, wu);
  build_big_kernel<<<6144, 256, 0, stream>>>(w_down, scales, 2, 256, 96, wd);
  cvt_x_kernel<<<12288, 256, 0, stream>>>(x, xb);
  gemm1_kernel<<<8192, 256, 0, stream>>>(xb, wg, wu, scales, h);
  gemm2_kernel<<<1536, 256, 0, stream>>>(h, wd, scales, out);
}